// Round 8
// baseline (814.128 us; speedup 1.0000x reference)
//
#include <hip/hip_runtime.h>
#include <stdint.h>

typedef __attribute__((ext_vector_type(8))) short bf16x8;
typedef __attribute__((ext_vector_type(4))) float f32x4;
typedef __attribute__((ext_vector_type(4))) int i32x4;
typedef __attribute__((ext_vector_type(2))) float f32x2;
typedef __attribute__((ext_vector_type(4))) unsigned int u32x4;
typedef __attribute__((ext_vector_type(8))) unsigned short ushort8_t;

__device__ __forceinline__ unsigned short f2bf(float f) {
    unsigned int u = __float_as_uint(f);
    u += 0x7FFFu + ((u >> 16) & 1u);
    return (unsigned short)(u >> 16);
}
// packed f32x2 -> bf16x2 (RNE); no builtin on gfx950 -> inline asm (T12)
__device__ __forceinline__ unsigned int cvt_pk_bf16(float lo, float hi) {
    unsigned int r;
    asm("v_cvt_pk_bf16_f32 %0, %1, %2" : "=v"(r) : "v"(lo), "v"(hi));
    return r;
}
// OCP e4m3fn encode (RNE) via exponent-shift trick; input pre-scaled into range.
__device__ __forceinline__ unsigned char fp8_enc(float f) {
    f = fminf(fmaxf(f, -448.f), 448.f);
    unsigned int u = __float_as_uint(f * 0x1p-120f);
    u += 0x7FFFFu + ((u >> 20) & 1u);
    return (unsigned char)(((u >> 20) & 0x7F) | ((u >> 24) & 0x80));
}

// packed fp8->f32 decode: word 0 = bytes 0,1 ; word 1 = bytes 2,3
__device__ __forceinline__ f32x2 cvtpk0(unsigned int u) {
#if __has_builtin(__builtin_amdgcn_cvt_pk_f32_fp8)
    auto r = __builtin_amdgcn_cvt_pk_f32_fp8((int)u, false);
    f32x2 o; o.x = r[0]; o.y = r[1]; return o;
#else
    f32x2 o;
    o.x = __builtin_amdgcn_cvt_f32_fp8(u, 0);
    o.y = __builtin_amdgcn_cvt_f32_fp8(u, 1);
    return o;
#endif
}
__device__ __forceinline__ f32x2 cvtpk1(unsigned int u) {
#if __has_builtin(__builtin_amdgcn_cvt_pk_f32_fp8)
    auto r = __builtin_amdgcn_cvt_pk_f32_fp8((int)u, true);
    f32x2 o; o.x = r[0]; o.y = r[1]; return o;
#else
    f32x2 o;
    o.x = __builtin_amdgcn_cvt_f32_fp8(u, 2);
    o.y = __builtin_amdgcn_cvt_f32_fp8(u, 3);
    return o;
#endif
}

// async global->LDS, 16B per lane. LDS dest must be wave-uniform base + lane*16
// (both call sites write LDS linearly in tid*16 -> satisfied).
__device__ __forceinline__ void gload_lds16(const void* g, void* l) {
    __builtin_amdgcn_global_load_lds(
        (const __attribute__((address_space(1))) void*)g,
        (__attribute__((address_space(3))) void*)l, 16, 0, 0);
}

#define SLAB_CAP 5120

// ---------------- bucketed CSR build (slab variant) ----------------
__global__ __launch_bounds__(256) void k_bscatter(const int* __restrict__ src,
                                                  const int* __restrict__ dst, int E,
                                                  int* __restrict__ bcnt,
                                                  int* __restrict__ slab, int nbuck) {
    __shared__ int lh[1024];
    __shared__ int lcur[1024];
    const int CH = 8192;
    int e0 = blockIdx.x * CH;
    int e1 = min(E, e0 + CH);
    for (int i = threadIdx.x; i < nbuck; i += 256) lh[i] = 0;
    __syncthreads();
    for (int i = e0 + threadIdx.x; i < e1; i += 256) atomicAdd(&lh[dst[i] >> 7], 1);
    __syncthreads();
    for (int i = threadIdx.x; i < nbuck; i += 256) {
        int c = lh[i];
        lh[i] = c ? atomicAdd(&bcnt[i], c) : 0;
        lcur[i] = 0;
    }
    __syncthreads();
    for (int i = e0 + threadIdx.x; i < e1; i += 256) {
        int d = dst[i], s = src[i];
        int b = d >> 7;
        int p = lh[b] + atomicAdd(&lcur[b], 1);
        if (p < SLAB_CAP) slab[(size_t)b * SLAB_CAP + p] = ((d & 127) << 20) | s;
    }
}

__global__ __launch_bounds__(1024) void k_bscan(const int* __restrict__ bcnt,
                                                int* __restrict__ bbase, int nbuck) {
    __shared__ int sh[1024];
    int t = threadIdx.x;
    int v = (t < nbuck) ? min(bcnt[t], SLAB_CAP) : 0;
    sh[t] = v;
    __syncthreads();
    for (int off = 1; off < 1024; off <<= 1) {
        int x = (t >= off) ? sh[t - off] : 0;
        __syncthreads();
        sh[t] += x;
        __syncthreads();
    }
    if (t < nbuck) bbase[t] = sh[t] - v;
    if (t == 1023) bbase[nbuck] = sh[1023];
}

// identical to the R5-proven version (no sort inside).
__global__ __launch_bounds__(256) void k_bcsr(const int* __restrict__ slab,
                                              const int* __restrict__ bcnt,
                                              const int* __restrict__ bbase,
                                              int* __restrict__ rowp,
                                              int* __restrict__ col,
                                              float* __restrict__ dinv, int n, int nbuck) {
    __shared__ int lh[128], lsc[128], lcur[128];
    const int b = blockIdx.x;
    const int base = bbase[b];
    const int cnt = min(bcnt[b], SLAB_CAP);
    const int t = threadIdx.x;
    const int* sl = slab + (size_t)b * SLAB_CAP;
    if (t < 128) lh[t] = 0;
    __syncthreads();
    for (int i = t; i < cnt; i += 256) atomicAdd(&lh[sl[i] >> 20], 1);
    __syncthreads();
    if (t < 128) lsc[t] = lh[t];
    __syncthreads();
    for (int off = 1; off < 128; off <<= 1) {
        int x = (t < 128 && t >= off) ? lsc[t - off] : 0;
        __syncthreads();
        if (t < 128) lsc[t] += x;
        __syncthreads();
    }
    if (t < 128) {
        int excl = lsc[t] - lh[t];
        lcur[t] = excl;
        int v = (b << 7) + t;
        if (v < n) {
            rowp[v] = base + excl;
            dinv[v] = rsqrtf((float)lh[t] + 1.0f);  // +1 self-loop
        }
    }
    if (b == 0 && t == 0) rowp[n] = bbase[nbuck];
    __syncthreads();
    for (int i = t; i < cnt; i += 256) {
        int pk = sl[i];
        int d = pk >> 20;
        int p = base + atomicAdd(&lcur[d], 1);
        col[p] = pk & 0xFFFFF;
    }
}

// ---------------- per-dst col sort (isolated kernel) ----------------
// One dst per thread; LDS insertion sort (stride-97 pad). Sorted source lists
// give agg1/agg2 monotone gather address streams (DRAM row + L2 line locality).
// Audited: cw<=96, col accesses within [e0,e0+cw) subset of colarr; no barriers.
__global__ __launch_bounds__(128) void k_sortcol(const int* __restrict__ rowp,
                                                 int* __restrict__ col, int n) {
    __shared__ int sbuf[128 * 97];  // 49.7 KB
    const int t = threadIdx.x;
    const int v = blockIdx.x * 128 + t;
    if (v >= n) return;
    const int e0 = rowp[v], e1 = rowp[v + 1];
    int cw = e1 - e0;
    if (cw > 96) cw = 96;  // P(deg>96) ~ 0 for Poisson(32); partial sort is harmless
    if (cw < 2) return;
    int* sb = sbuf + t * 97;
    for (int i = 0; i < cw; i++) sb[i] = col[e0 + i];
    for (int i = 1; i < cw; i++) {
        int key = sb[i];
        int j = i - 1;
        while (j >= 0 && sb[j] > key) { sb[j + 1] = sb[j]; j--; }
        sb[j + 1] = key;
    }
    for (int i = 0; i < cw; i++) col[e0 + i] = sb[i];
}

// ---------------- weight prep ----------------
__global__ __launch_bounds__(256) void k_cvt_w(const float* __restrict__ W1,
                                               const float* __restrict__ W2,
                                               short* __restrict__ W1t,
                                               short* __restrict__ W2t,
                                               int n1, int n2) {
    int i = blockIdx.x * blockDim.x + threadIdx.x;
    if (i < n1) {
        int k = i >> 8, c = i & 255;
        W1t[(size_t)c * 512 + k] = (short)f2bf(W1[i]);
    } else if (i < n1 + n2) {
        int i2 = i - n1;
        int k = i2 / 40, c = i2 - k * 40;
        W2t[(size_t)c * 256 + k] = (short)f2bf(W2[i2]);
    }
}

// ---------------- GEMM1: A f32 [M][512] x W1t bf16 [256][512] -> h1p fp8 [M][256] ---
__global__ __launch_bounds__(512) void k_gemm1(const float* __restrict__ A,
                                               const short* __restrict__ Bt,
                                               const float* __restrict__ dinv,
                                               unsigned char* __restrict__ outp, int M) {
    const int K = 512;
    __shared__ __align__(16) short As[128 * 32];
    __shared__ __align__(16) short Bs[256 * 32];
    const int tid = threadIdx.x;
    const int m0 = blockIdx.x * 128;
    const int w = tid >> 6, lane = tid & 63;
    const int quad = lane >> 4, l16 = lane & 15;
    const int mbase = (w >> 2) * 64, nbase = (w & 3) * 64;

    f32x4 acc[4][4];
#pragma unroll
    for (int i = 0; i < 4; i++)
#pragma unroll
        for (int j = 0; j < 4; j++) acc[i][j] = (f32x4){0.f, 0.f, 0.f, 0.f};

    for (int k0 = 0; k0 < K; k0 += 32) {
        // B: async direct-to-LDS first (latency hidden under A staging)
#pragma unroll
        for (int s = tid; s < 1024; s += 512) {
            int r = s >> 2, seg = s & 3;
            gload_lds16(Bt + (size_t)r * K + k0 + seg * 8, Bs + s * 8);
        }
        // A: f32 -> bf16 via VGPRs (conversion needed; can't direct-to-LDS)
#pragma unroll
        for (int s = tid; s < 1024; s += 512) {
            int r = s >> 3, seg = s & 7;
            int gr = m0 + r;
            if (gr >= M) gr = M - 1;
            float4 v = *(const float4*)(A + (size_t)gr * K + k0 + seg * 4);
            uint2 o;
            o.x = cvt_pk_bf16(v.x, v.y);
            o.y = cvt_pk_bf16(v.z, v.w);
            *(uint2*)(As + r * 32 + seg * 4) = o;
        }
        __syncthreads();  // drains vmcnt (B) + lgkmcnt (A)
        bf16x8 af[4], bfr[4];
#pragma unroll
        for (int i = 0; i < 4; i++)
            af[i] = *(const bf16x8*)(As + (mbase + i * 16 + l16) * 32 + quad * 8);
#pragma unroll
        for (int j = 0; j < 4; j++)
            bfr[j] = *(const bf16x8*)(Bs + (nbase + j * 16 + l16) * 32 + quad * 8);
#pragma unroll
        for (int i = 0; i < 4; i++)
#pragma unroll
            for (int j = 0; j < 4; j++)
                acc[i][j] = __builtin_amdgcn_mfma_f32_16x16x32_bf16(af[i], bfr[j], acc[i][j], 0, 0, 0);
        __syncthreads();
    }

#pragma unroll
    for (int i = 0; i < 4; i++) {
#pragma unroll
        for (int r = 0; r < 4; r++) {
            int row = m0 + mbase + i * 16 + quad * 4 + r;
            if (row < M) {
                float dv = dinv[row] * 64.f;  // fp8 range scale; undone in agg1
#pragma unroll
                for (int j = 0; j < 4; j++)
                    outp[(size_t)row * 256 + nbase + j * 16 + l16] =
                        fp8_enc(acc[i][j][r] * dv);
            }
        }
    }
}

// ---------------- GEMM2: h2 bf16 [M][256] x W2t bf16 [64][256] -> zp fp8 [M][64] ----
__global__ __launch_bounds__(256) void k_gemm2(const short* __restrict__ A,
                                               const short* __restrict__ Bt,
                                               const float* __restrict__ dinv,
                                               unsigned char* __restrict__ outp, int M) {
    const int K = 256;
    __shared__ __align__(16) short As[128 * 32];
    __shared__ __align__(16) short Bs[64 * 32];
    const int tid = threadIdx.x;
    const int m0 = blockIdx.x * 128;
    const int w = tid >> 6, lane = tid & 63;
    const int quad = lane >> 4, l16 = lane & 15;
    const int mbase = (w >> 1) * 64, nbase = (w & 1) * 32;

    f32x4 acc[4][2];
#pragma unroll
    for (int i = 0; i < 4; i++)
#pragma unroll
        for (int j = 0; j < 2; j++) acc[i][j] = (f32x4){0.f, 0.f, 0.f, 0.f};

    for (int k0 = 0; k0 < K; k0 += 32) {
#pragma unroll
        for (int s = tid; s < 512; s += 256) {
            int r = s >> 2, seg = s & 3;
            int gr = m0 + r;
            if (gr >= M) gr = M - 1;
            gload_lds16(A + (size_t)gr * K + k0 + seg * 8, As + s * 8);
        }
        if (tid < 256) {
            int r = tid >> 2, seg = tid & 3;
            gload_lds16(Bt + (size_t)r * K + k0 + seg * 8, Bs + tid * 8);
        }
        __syncthreads();
        bf16x8 af[4], bfr[2];
#pragma unroll
        for (int i = 0; i < 4; i++)
            af[i] = *(const bf16x8*)(As + (mbase + i * 16 + l16) * 32 + quad * 8);
#pragma unroll
        for (int j = 0; j < 2; j++)
            bfr[j] = *(const bf16x8*)(Bs + (nbase + j * 16 + l16) * 32 + quad * 8);
#pragma unroll
        for (int i = 0; i < 4; i++)
#pragma unroll
            for (int j = 0; j < 2; j++)
                acc[i][j] = __builtin_amdgcn_mfma_f32_16x16x32_bf16(af[i], bfr[j], acc[i][j], 0, 0, 0);
        __syncthreads();
    }

#pragma unroll
    for (int i = 0; i < 4; i++) {
#pragma unroll
        for (int r = 0; r < 4; r++) {
            int row = m0 + mbase + i * 16 + quad * 4 + r;
            if (row < M) {
                float dv = dinv[row] * 64.f;  // fp8 range scale; undone in agg2
#pragma unroll
                for (int j = 0; j < 2; j++)
                    outp[(size_t)row * 64 + nbase + j * 16 + l16] =
                        fp8_enc(acc[i][j][r] * dv);
            }
        }
    }
}

// ---------------- aggregation layer 1 (256 feats, fp8 payload), bias+relu ----------
// R1-proven structure (129 us). Sorted col (k_sortcol) makes each wave's in-flight
// gathers a monotone address stream.
__global__ __launch_bounds__(256) void k_agg1(const unsigned char* __restrict__ h1p,
                                              const int* __restrict__ rowp,
                                              const int* __restrict__ col,
                                              const float* __restrict__ dinv,
                                              const float* __restrict__ b1,
                                              short* __restrict__ h2, int n) {
    const u32x4* __restrict__ hq = (const u32x4*)h1p;  // 16 x 16B per row
    const int w = threadIdx.x >> 6, lane = threadIdx.x & 63;
    const int g = lane >> 4, sl = lane & 15;  // 4 edge-groups x 16 lanes
    const int v = blockIdx.x * 4 + w;         // one dst per wave
    if (v >= n) return;

    f32x2 acc[8];  // 16 feats per lane: feats sl*16 .. sl*16+15
    {
        u32x4 q = (u32x4){0u, 0u, 0u, 0u};
        if (g == 0) q = hq[(size_t)v * 16 + sl];  // self-loop once (group 0)
#pragma unroll
        for (int i = 0; i < 4; i++) {
            acc[2 * i] = cvtpk0(q[i]);
            acc[2 * i + 1] = cvtpk1(q[i]);
        }
    }

    const int e0 = rowp[v], e1 = rowp[v + 1];
    const int nedge = e1 - e0;
    const int full = nedge & ~7;  // wave-uniform
    for (int t = 0; t < full; t += 8) {
        int ea = e0 + t + g;
        int sa = col[ea], sb = col[ea + 4];
        u32x4 qa = hq[(size_t)sa * 16 + sl];
        u32x4 qb = hq[(size_t)sb * 16 + sl];
#pragma unroll
        for (int i = 0; i < 4; i++) {
            acc[2 * i] += cvtpk0(qa[i]);
            acc[2 * i + 1] += cvtpk1(qa[i]);
        }
#pragma unroll
        for (int i = 0; i < 4; i++) {
            acc[2 * i] += cvtpk0(qb[i]);
            acc[2 * i + 1] += cvtpk1(qb[i]);
        }
    }
    for (int t = full + g; t < nedge; t += 4) {  // tail: <=2 predicated rounds
        u32x4 q = hq[(size_t)col[e0 + t] * 16 + sl];
#pragma unroll
        for (int i = 0; i < 4; i++) {
            acc[2 * i] += cvtpk0(q[i]);
            acc[2 * i + 1] += cvtpk1(q[i]);
        }
    }

    // reduce across the 4 edge-groups (once per dst)
#pragma unroll
    for (int i = 0; i < 8; i++) {
        acc[i].x += __shfl_xor(acc[i].x, 16);
        acc[i].y += __shfl_xor(acc[i].y, 16);
        acc[i].x += __shfl_xor(acc[i].x, 32);
        acc[i].y += __shfl_xor(acc[i].y, 32);
    }

    if (g < 2) {  // groups 0,1 each store 16B -> one 512B coalesced row store
        const float dv = dinv[v] * 0x1p-6f;  // undo fp8 range scale (64)
        const float4* bq = (const float4*)(b1 + sl * 16 + g * 8);
        ushort8_t o;
#pragma unroll
        for (int k = 0; k < 2; k++) {
            float4 bb = bq[k];
            f32x2 p0 = acc[g * 4 + k * 2];
            f32x2 p1 = acc[g * 4 + k * 2 + 1];
            o[k * 4 + 0] = f2bf(fmaxf(fmaf(dv, p0.x, bb.x), 0.f));
            o[k * 4 + 1] = f2bf(fmaxf(fmaf(dv, p0.y, bb.y), 0.f));
            o[k * 4 + 2] = f2bf(fmaxf(fmaf(dv, p1.x, bb.z), 0.f));
            o[k * 4 + 3] = f2bf(fmaxf(fmaf(dv, p1.y, bb.w), 0.f));
        }
        *(ushort8_t*)(h2 + (size_t)v * 256 + sl * 16 + g * 8) = o;
    }
}

// ---------------- aggregation layer 2 (fp8 zp, 64B rows) + bias + log_softmax -------
__global__ __launch_bounds__(256) void k_agg2(const unsigned char* __restrict__ zp,
                                              const int* __restrict__ rowp,
                                              const int* __restrict__ col,
                                              const float* __restrict__ dinv,
                                              const float* __restrict__ b2,
                                              float* __restrict__ out, int n) {
    const unsigned int* __restrict__ zw = (const unsigned int*)zp;  // 16 uints/row
    const int w = threadIdx.x >> 6, lane = threadIdx.x & 63;
    const int g = lane >> 4, sl = lane & 15;
    const int v = blockIdx.x * 16 + w * 4 + g;
    if (v >= n) return;
    f32x2 a01, a23;
    {
        unsigned int u = zw[(size_t)v * 16 + sl];  // self-loop
        a01 = cvtpk0(u);
        a23 = cvtpk1(u);
    }
    const int e0 = rowp[v], e1 = rowp[v + 1];
    int e = e0;
    for (; e + 8 <= e1; e += 8) {
        int s0 = col[e], s1 = col[e + 1], s2 = col[e + 2], s3 = col[e + 3];
        int s4 = col[e + 4], s5 = col[e + 5], s6 = col[e + 6], s7 = col[e + 7];
        unsigned int u0 = zw[(size_t)s0 * 16 + sl];
        unsigned int u1 = zw[(size_t)s1 * 16 + sl];
        unsigned int u2 = zw[(size_t)s2 * 16 + sl];
        unsigned int u3 = zw[(size_t)s3 * 16 + sl];
        unsigned int u4 = zw[(size_t)s4 * 16 + sl];
        unsigned int u5 = zw[(size_t)s5 * 16 + sl];
        unsigned int u6 = zw[(size_t)s6 * 16 + sl];
        unsigned int u7 = zw[(size_t)s7 * 16 + sl];
        a01 += cvtpk0(u0) + cvtpk0(u1) + cvtpk0(u2) + cvtpk0(u3)
             + cvtpk0(u4) + cvtpk0(u5) + cvtpk0(u6) + cvtpk0(u7);
        a23 += cvtpk1(u0) + cvtpk1(u1) + cvtpk1(u2) + cvtpk1(u3)
             + cvtpk1(u4) + cvtpk1(u5) + cvtpk1(u6) + cvtpk1(u7);
    }
    for (; e + 2 <= e1; e += 2) {
        unsigned int u0 = zw[(size_t)col[e] * 16 + sl];
        unsigned int u1 = zw[(size_t)col[e + 1] * 16 + sl];
        a01 += cvtpk0(u0) + cvtpk0(u1);
        a23 += cvtpk1(u0) + cvtpk1(u1);
    }
    for (; e < e1; e++) {
        unsigned int u = zw[(size_t)col[e] * 16 + sl];
        a01 += cvtpk0(u);
        a23 += cvtpk1(u);
    }
    const int f = sl * 4;
    const float dv = dinv[v] * 0x1p-6f;  // undo fp8 range scale (64)
    float l0 = (f + 0 < 40) ? fmaf(dv, a01.x, b2[f + 0]) : -1e30f;
    float l1 = (f + 1 < 40) ? fmaf(dv, a01.y, b2[f + 1]) : -1e30f;
    float l2 = (f + 2 < 40) ? fmaf(dv, a23.x, b2[f + 2]) : -1e30f;
    float l3 = (f + 3 < 40) ? fmaf(dv, a23.y, b2[f + 3]) : -1e30f;
    float m = fmaxf(fmaxf(l0, l1), fmaxf(l2, l3));
    m = fmaxf(m, __shfl_xor(m, 1));
    m = fmaxf(m, __shfl_xor(m, 2));
    m = fmaxf(m, __shfl_xor(m, 4));
    m = fmaxf(m, __shfl_xor(m, 8));
    float es = expf(l0 - m) + expf(l1 - m) + expf(l2 - m) + expf(l3 - m);
    es += __shfl_xor(es, 1);
    es += __shfl_xor(es, 2);
    es += __shfl_xor(es, 4);
    es += __shfl_xor(es, 8);
    float ls = m + logf(es);
    if (sl < 10) {
        float4 o = {l0 - ls, l1 - ls, l2 - ls, l3 - ls};
        *(float4*)(out + (size_t)v * 40 + f) = o;
    }
}

extern "C" void kernel_launch(void* const* d_in, const int* in_sizes, int n_in,
                              void* d_out, int out_size, void* d_ws, size_t ws_size,
                              hipStream_t stream) {
    const float* x  = (const float*)d_in[0];
    const float* W1 = (const float*)d_in[1];
    const float* b1 = (const float*)d_in[2];
    const float* W2 = (const float*)d_in[3];
    const float* b2 = (const float*)d_in[4];
    const int*   ei = (const int*)d_in[5];
    float* out = (float*)d_out;

    const int FIN = 512, H = 256, C = 40;
    const int n = in_sizes[0] / FIN;   // 100000
    const int E = in_sizes[5] / 2;     // 3200000
    const int nbuck = (n + 127) >> 7;  // 782

    auto align_up = [](size_t v) { return (v + 255) & ~(size_t)255; };
    char* base = (char*)d_ws;
    size_t off = 0;
    unsigned char* h1p = (unsigned char*)(base + off); off += align_up((size_t)n * H);
    short* h2    = (short*)(base + off); off += align_up((size_t)n * H * 2);
    unsigned char* zp = (unsigned char*)(base + off); off += align_up((size_t)n * 64);
    float* dinv  = (float*)(base + off); off += align_up((size_t)n * 4);
    int* rowp    = (int*)(base + off);   off += align_up((size_t)(n + 1) * 4);
    int* colarr  = (int*)(base + off);   off += align_up((size_t)E * 4);
    int* slab    = (int*)(base + off);   off += align_up((size_t)nbuck * SLAB_CAP * 4);
    short* W1t   = (short*)(base + off); off += align_up((size_t)H * FIN * 2);
    short* W2t   = (short*)(base + off); off += align_up((size_t)64 * H * 2);
    int* bcnt    = (int*)(base + off);   off += align_up((size_t)(nbuck + 1) * 4);
    int* bbase   = (int*)(base + off);   off += align_up((size_t)(nbuck + 1) * 4);

    const int* srcp = ei;
    const int* dstp = ei + E;

    hipMemsetAsync(bcnt, 0, (size_t)(nbuck + 1) * 4, stream);
    hipMemsetAsync(W2t, 0, (size_t)64 * H * 2, stream);

    // CSR build (slab-bucketed), then per-dst sort in an isolated kernel
    k_bscatter<<<(E + 8191) / 8192, 256, 0, stream>>>(srcp, dstp, E, bcnt, slab, nbuck);
    k_bscan<<<1, 1024, 0, stream>>>(bcnt, bbase, nbuck);
    k_bcsr<<<nbuck, 256, 0, stream>>>(slab, bcnt, bbase, rowp, colarr, dinv, n, nbuck);
    k_sortcol<<<(n + 127) / 128, 128, 0, stream>>>(rowp, colarr, n);

    // weight prep
    int n1 = FIN * H, n2 = H * C;
    k_cvt_w<<<(n1 + n2 + 255) / 256, 256, 0, stream>>>(W1, W2, W1t, W2t, n1, n2);

    // layer 1: fused cast+GEMM -> fp8 h1p; row-gather aggregation -> h2
    k_gemm1<<<(n + 127) / 128, 512, 0, stream>>>(x, W1t, dinv, h1p, n);
    k_agg1<<<(n + 3) / 4, 256, 0, stream>>>(h1p, rowp, colarr, dinv, b1, h2, n);

    // layer 2: GEMM -> fp8 zp (64B rows); one-line-per-edge aggregation + log_softmax
    k_gemm2<<<(n + 127) / 128, 256, 0, stream>>>(h2, W2t, dinv, zp, n);
    k_agg2<<<(n + 15) / 16, 256, 0, stream>>>(zp, rowp, colarr, dinv, b2, out, n);
}

// Round 9
// 672.637 us; speedup vs baseline: 1.2104x; 1.2104x over previous
//
#include <hip/hip_runtime.h>
#include <stdint.h>

typedef __attribute__((ext_vector_type(8))) short bf16x8;
typedef __attribute__((ext_vector_type(4))) float f32x4;
typedef __attribute__((ext_vector_type(4))) int i32x4;
typedef __attribute__((ext_vector_type(2))) float f32x2;
typedef __attribute__((ext_vector_type(4))) unsigned int u32x4;
typedef __attribute__((ext_vector_type(8))) unsigned short ushort8_t;

__device__ __forceinline__ unsigned short f2bf(float f) {
    unsigned int u = __float_as_uint(f);
    u += 0x7FFFu + ((u >> 16) & 1u);
    return (unsigned short)(u >> 16);
}
// packed f32x2 -> bf16x2 (RNE); no builtin on gfx950 -> inline asm (T12)
__device__ __forceinline__ unsigned int cvt_pk_bf16(float lo, float hi) {
    unsigned int r;
    asm("v_cvt_pk_bf16_f32 %0, %1, %2" : "=v"(r) : "v"(lo), "v"(hi));
    return r;
}
// OCP e4m3fn encode (RNE) via exponent-shift trick; input pre-scaled into range.
__device__ __forceinline__ unsigned char fp8_enc(float f) {
    f = fminf(fmaxf(f, -448.f), 448.f);
    unsigned int u = __float_as_uint(f * 0x1p-120f);
    u += 0x7FFFFu + ((u >> 20) & 1u);
    return (unsigned char)(((u >> 20) & 0x7F) | ((u >> 24) & 0x80));
}

// packed fp8->f32 decode: word 0 = bytes 0,1 ; word 1 = bytes 2,3
__device__ __forceinline__ f32x2 cvtpk0(unsigned int u) {
#if __has_builtin(__builtin_amdgcn_cvt_pk_f32_fp8)
    auto r = __builtin_amdgcn_cvt_pk_f32_fp8((int)u, false);
    f32x2 o; o.x = r[0]; o.y = r[1]; return o;
#else
    f32x2 o;
    o.x = __builtin_amdgcn_cvt_f32_fp8(u, 0);
    o.y = __builtin_amdgcn_cvt_f32_fp8(u, 1);
    return o;
#endif
}
__device__ __forceinline__ f32x2 cvtpk1(unsigned int u) {
#if __has_builtin(__builtin_amdgcn_cvt_pk_f32_fp8)
    auto r = __builtin_amdgcn_cvt_pk_f32_fp8((int)u, true);
    f32x2 o; o.x = r[0]; o.y = r[1]; return o;
#else
    f32x2 o;
    o.x = __builtin_amdgcn_cvt_f32_fp8(u, 2);
    o.y = __builtin_amdgcn_cvt_f32_fp8(u, 3);
    return o;
#endif
}

// async global->LDS, 16B per lane. LDS dest must be wave-uniform base + lane*16
// (both call sites write LDS linearly in tid*16 -> satisfied).
__device__ __forceinline__ void gload_lds16(const void* g, void* l) {
    __builtin_amdgcn_global_load_lds(
        (const __attribute__((address_space(1))) void*)g,
        (__attribute__((address_space(3))) void*)l, 16, 0, 0);
}

#define SLAB_CAP 5120

// ---------------- bucketed CSR build (slab variant) ----------------
__global__ __launch_bounds__(256) void k_bscatter(const int* __restrict__ src,
                                                  const int* __restrict__ dst, int E,
                                                  int* __restrict__ bcnt,
                                                  int* __restrict__ slab, int nbuck) {
    __shared__ int lh[1024];
    __shared__ int lcur[1024];
    const int CH = 8192;
    int e0 = blockIdx.x * CH;
    int e1 = min(E, e0 + CH);
    for (int i = threadIdx.x; i < nbuck; i += 256) lh[i] = 0;
    __syncthreads();
    for (int i = e0 + threadIdx.x; i < e1; i += 256) atomicAdd(&lh[dst[i] >> 7], 1);
    __syncthreads();
    for (int i = threadIdx.x; i < nbuck; i += 256) {
        int c = lh[i];
        lh[i] = c ? atomicAdd(&bcnt[i], c) : 0;
        lcur[i] = 0;
    }
    __syncthreads();
    for (int i = e0 + threadIdx.x; i < e1; i += 256) {
        int d = dst[i], s = src[i];
        int b = d >> 7;
        int p = lh[b] + atomicAdd(&lcur[b], 1);
        if (p < SLAB_CAP) slab[(size_t)b * SLAB_CAP + p] = ((d & 127) << 20) | s;
    }
}

__global__ __launch_bounds__(1024) void k_bscan(const int* __restrict__ bcnt,
                                                int* __restrict__ bbase, int nbuck) {
    __shared__ int sh[1024];
    int t = threadIdx.x;
    int v = (t < nbuck) ? min(bcnt[t], SLAB_CAP) : 0;
    sh[t] = v;
    __syncthreads();
    for (int off = 1; off < 1024; off <<= 1) {
        int x = (t >= off) ? sh[t - off] : 0;
        __syncthreads();
        sh[t] += x;
        __syncthreads();
    }
    if (t < nbuck) bbase[t] = sh[t] - v;
    if (t == 1023) bbase[nbuck] = sh[1023];
}

// identical to the R5-proven version (no sort inside).
__global__ __launch_bounds__(256) void k_bcsr(const int* __restrict__ slab,
                                              const int* __restrict__ bcnt,
                                              const int* __restrict__ bbase,
                                              int* __restrict__ rowp,
                                              int* __restrict__ col,
                                              float* __restrict__ dinv, int n, int nbuck) {
    __shared__ int lh[128], lsc[128], lcur[128];
    const int b = blockIdx.x;
    const int base = bbase[b];
    const int cnt = min(bcnt[b], SLAB_CAP);
    const int t = threadIdx.x;
    const int* sl = slab + (size_t)b * SLAB_CAP;
    if (t < 128) lh[t] = 0;
    __syncthreads();
    for (int i = t; i < cnt; i += 256) atomicAdd(&lh[sl[i] >> 20], 1);
    __syncthreads();
    if (t < 128) lsc[t] = lh[t];
    __syncthreads();
    for (int off = 1; off < 128; off <<= 1) {
        int x = (t < 128 && t >= off) ? lsc[t - off] : 0;
        __syncthreads();
        if (t < 128) lsc[t] += x;
        __syncthreads();
    }
    if (t < 128) {
        int excl = lsc[t] - lh[t];
        lcur[t] = excl;
        int v = (b << 7) + t;
        if (v < n) {
            rowp[v] = base + excl;
            dinv[v] = rsqrtf((float)lh[t] + 1.0f);  // +1 self-loop
        }
    }
    if (b == 0 && t == 0) rowp[n] = bbase[nbuck];
    __syncthreads();
    for (int i = t; i < cnt; i += 256) {
        int pk = sl[i];
        int d = pk >> 20;
        int p = base + atomicAdd(&lcur[d], 1);
        col[p] = pk & 0xFFFFF;
    }
}

// ---------------- per-dst col sort: WAVE-PARALLEL RANK SORT ----------------
// One dst per wave. lane i holds key_i; rank via cw-iteration shfl broadcast
// (tie-break by lane -> unique ranks). Rows with deg>64 stay unsorted (valid
// permutation = identity; P(deg>64|Poisson 32) ~ 0). No LDS, ~cw*3 VALU/dst —
// replaces R8's 200us serial insertion sort (8% occ, 615K LDS conflicts).
__global__ __launch_bounds__(256) void k_sortcol(const int* __restrict__ rowp,
                                                 int* __restrict__ col, int n) {
    const int w = threadIdx.x >> 6, lane = threadIdx.x & 63;
    const int v = blockIdx.x * 4 + w;
    if (v >= n) return;
    const int e0 = rowp[v], e1 = rowp[v + 1];
    const int cw = e1 - e0;
    if (cw < 2 || cw > 64) return;  // wave-uniform branch
    int key = (lane < cw) ? col[e0 + lane] : 0x7FFFFFFF;
    int rank = 0;
    for (int j = 0; j < cw; j++) {
        int kj = __shfl(key, j);
        rank += (kj < key || (kj == key && j < lane)) ? 1 : 0;
    }
    if (lane < cw) col[e0 + rank] = key;
}

// ---------------- weight prep ----------------
__global__ __launch_bounds__(256) void k_cvt_w(const float* __restrict__ W1,
                                               const float* __restrict__ W2,
                                               short* __restrict__ W1t,
                                               short* __restrict__ W2t,
                                               int n1, int n2) {
    int i = blockIdx.x * blockDim.x + threadIdx.x;
    if (i < n1) {
        int k = i >> 8, c = i & 255;
        W1t[(size_t)c * 512 + k] = (short)f2bf(W1[i]);
    } else if (i < n1 + n2) {
        int i2 = i - n1;
        int k = i2 / 40, c = i2 - k * 40;
        W2t[(size_t)c * 256 + k] = (short)f2bf(W2[i2]);
    }
}

// ---------------- GEMM1: A f32 [M][512] x W1t bf16 [256][512] -> h1p fp8 [M][256] ---
__global__ __launch_bounds__(512) void k_gemm1(const float* __restrict__ A,
                                               const short* __restrict__ Bt,
                                               const float* __restrict__ dinv,
                                               unsigned char* __restrict__ outp, int M) {
    const int K = 512;
    __shared__ __align__(16) short As[128 * 32];
    __shared__ __align__(16) short Bs[256 * 32];
    const int tid = threadIdx.x;
    const int m0 = blockIdx.x * 128;
    const int w = tid >> 6, lane = tid & 63;
    const int quad = lane >> 4, l16 = lane & 15;
    const int mbase = (w >> 2) * 64, nbase = (w & 3) * 64;

    f32x4 acc[4][4];
#pragma unroll
    for (int i = 0; i < 4; i++)
#pragma unroll
        for (int j = 0; j < 4; j++) acc[i][j] = (f32x4){0.f, 0.f, 0.f, 0.f};

    for (int k0 = 0; k0 < K; k0 += 32) {
        // B: async direct-to-LDS first (latency hidden under A staging)
#pragma unroll
        for (int s = tid; s < 1024; s += 512) {
            int r = s >> 2, seg = s & 3;
            gload_lds16(Bt + (size_t)r * K + k0 + seg * 8, Bs + s * 8);
        }
        // A: f32 -> bf16 via VGPRs (conversion needed; can't direct-to-LDS)
#pragma unroll
        for (int s = tid; s < 1024; s += 512) {
            int r = s >> 3, seg = s & 7;
            int gr = m0 + r;
            if (gr >= M) gr = M - 1;
            float4 v = *(const float4*)(A + (size_t)gr * K + k0 + seg * 4);
            uint2 o;
            o.x = cvt_pk_bf16(v.x, v.y);
            o.y = cvt_pk_bf16(v.z, v.w);
            *(uint2*)(As + r * 32 + seg * 4) = o;
        }
        __syncthreads();  // drains vmcnt (B) + lgkmcnt (A)
        bf16x8 af[4], bfr[4];
#pragma unroll
        for (int i = 0; i < 4; i++)
            af[i] = *(const bf16x8*)(As + (mbase + i * 16 + l16) * 32 + quad * 8);
#pragma unroll
        for (int j = 0; j < 4; j++)
            bfr[j] = *(const bf16x8*)(Bs + (nbase + j * 16 + l16) * 32 + quad * 8);
#pragma unroll
        for (int i = 0; i < 4; i++)
#pragma unroll
            for (int j = 0; j < 4; j++)
                acc[i][j] = __builtin_amdgcn_mfma_f32_16x16x32_bf16(af[i], bfr[j], acc[i][j], 0, 0, 0);
        __syncthreads();
    }

#pragma unroll
    for (int i = 0; i < 4; i++) {
#pragma unroll
        for (int r = 0; r < 4; r++) {
            int row = m0 + mbase + i * 16 + quad * 4 + r;
            if (row < M) {
                float dv = dinv[row] * 64.f;  // fp8 range scale; undone in agg1
#pragma unroll
                for (int j = 0; j < 4; j++)
                    outp[(size_t)row * 256 + nbase + j * 16 + l16] =
                        fp8_enc(acc[i][j][r] * dv);
            }
        }
    }
}

// ---------------- GEMM2: h2 bf16 [M][256] x W2t bf16 [64][256] -> zp fp8 [M][64] ----
__global__ __launch_bounds__(256) void k_gemm2(const short* __restrict__ A,
                                               const short* __restrict__ Bt,
                                               const float* __restrict__ dinv,
                                               unsigned char* __restrict__ outp, int M) {
    const int K = 256;
    __shared__ __align__(16) short As[128 * 32];
    __shared__ __align__(16) short Bs[64 * 32];
    const int tid = threadIdx.x;
    const int m0 = blockIdx.x * 128;
    const int w = tid >> 6, lane = tid & 63;
    const int quad = lane >> 4, l16 = lane & 15;
    const int mbase = (w >> 1) * 64, nbase = (w & 1) * 32;

    f32x4 acc[4][2];
#pragma unroll
    for (int i = 0; i < 4; i++)
#pragma unroll
        for (int j = 0; j < 2; j++) acc[i][j] = (f32x4){0.f, 0.f, 0.f, 0.f};

    for (int k0 = 0; k0 < K; k0 += 32) {
#pragma unroll
        for (int s = tid; s < 512; s += 256) {
            int r = s >> 2, seg = s & 3;
            int gr = m0 + r;
            if (gr >= M) gr = M - 1;
            gload_lds16(A + (size_t)gr * K + k0 + seg * 8, As + s * 8);
        }
        if (tid < 256) {
            int r = tid >> 2, seg = tid & 3;
            gload_lds16(Bt + (size_t)r * K + k0 + seg * 8, Bs + tid * 8);
        }
        __syncthreads();
        bf16x8 af[4], bfr[2];
#pragma unroll
        for (int i = 0; i < 4; i++)
            af[i] = *(const bf16x8*)(As + (mbase + i * 16 + l16) * 32 + quad * 8);
#pragma unroll
        for (int j = 0; j < 2; j++)
            bfr[j] = *(const bf16x8*)(Bs + (nbase + j * 16 + l16) * 32 + quad * 8);
#pragma unroll
        for (int i = 0; i < 4; i++)
#pragma unroll
            for (int j = 0; j < 2; j++)
                acc[i][j] = __builtin_amdgcn_mfma_f32_16x16x32_bf16(af[i], bfr[j], acc[i][j], 0, 0, 0);
        __syncthreads();
    }

#pragma unroll
    for (int i = 0; i < 4; i++) {
#pragma unroll
        for (int r = 0; r < 4; r++) {
            int row = m0 + mbase + i * 16 + quad * 4 + r;
            if (row < M) {
                float dv = dinv[row] * 64.f;  // fp8 range scale; undone in agg2
#pragma unroll
                for (int j = 0; j < 2; j++)
                    outp[(size_t)row * 64 + nbase + j * 16 + l16] =
                        fp8_enc(acc[i][j][r] * dv);
            }
        }
    }
}

// ---------------- aggregation layer 1 (256 feats, fp8 payload), bias+relu ----------
// R1-proven structure. Sorted col (k_sortcol) makes each wave's in-flight
// gathers a monotone address stream (measured: ~35-40us combined agg savings, R8).
__global__ __launch_bounds__(256) void k_agg1(const unsigned char* __restrict__ h1p,
                                              const int* __restrict__ rowp,
                                              const int* __restrict__ col,
                                              const float* __restrict__ dinv,
                                              const float* __restrict__ b1,
                                              short* __restrict__ h2, int n) {
    const u32x4* __restrict__ hq = (const u32x4*)h1p;  // 16 x 16B per row
    const int w = threadIdx.x >> 6, lane = threadIdx.x & 63;
    const int g = lane >> 4, sl = lane & 15;  // 4 edge-groups x 16 lanes
    const int v = blockIdx.x * 4 + w;         // one dst per wave
    if (v >= n) return;

    f32x2 acc[8];  // 16 feats per lane: feats sl*16 .. sl*16+15
    {
        u32x4 q = (u32x4){0u, 0u, 0u, 0u};
        if (g == 0) q = hq[(size_t)v * 16 + sl];  // self-loop once (group 0)
#pragma unroll
        for (int i = 0; i < 4; i++) {
            acc[2 * i] = cvtpk0(q[i]);
            acc[2 * i + 1] = cvtpk1(q[i]);
        }
    }

    const int e0 = rowp[v], e1 = rowp[v + 1];
    const int nedge = e1 - e0;
    const int full = nedge & ~7;  // wave-uniform
    for (int t = 0; t < full; t += 8) {
        int ea = e0 + t + g;
        int sa = col[ea], sb = col[ea + 4];
        u32x4 qa = hq[(size_t)sa * 16 + sl];
        u32x4 qb = hq[(size_t)sb * 16 + sl];
#pragma unroll
        for (int i = 0; i < 4; i++) {
            acc[2 * i] += cvtpk0(qa[i]);
            acc[2 * i + 1] += cvtpk1(qa[i]);
        }
#pragma unroll
        for (int i = 0; i < 4; i++) {
            acc[2 * i] += cvtpk0(qb[i]);
            acc[2 * i + 1] += cvtpk1(qb[i]);
        }
    }
    for (int t = full + g; t < nedge; t += 4) {  // tail: <=2 predicated rounds
        u32x4 q = hq[(size_t)col[e0 + t] * 16 + sl];
#pragma unroll
        for (int i = 0; i < 4; i++) {
            acc[2 * i] += cvtpk0(q[i]);
            acc[2 * i + 1] += cvtpk1(q[i]);
        }
    }

    // reduce across the 4 edge-groups (once per dst)
#pragma unroll
    for (int i = 0; i < 8; i++) {
        acc[i].x += __shfl_xor(acc[i].x, 16);
        acc[i].y += __shfl_xor(acc[i].y, 16);
        acc[i].x += __shfl_xor(acc[i].x, 32);
        acc[i].y += __shfl_xor(acc[i].y, 32);
    }

    if (g < 2) {  // groups 0,1 each store 16B -> one 512B coalesced row store
        const float dv = dinv[v] * 0x1p-6f;  // undo fp8 range scale (64)
        const float4* bq = (const float4*)(b1 + sl * 16 + g * 8);
        ushort8_t o;
#pragma unroll
        for (int k = 0; k < 2; k++) {
            float4 bb = bq[k];
            f32x2 p0 = acc[g * 4 + k * 2];
            f32x2 p1 = acc[g * 4 + k * 2 + 1];
            o[k * 4 + 0] = f2bf(fmaxf(fmaf(dv, p0.x, bb.x), 0.f));
            o[k * 4 + 1] = f2bf(fmaxf(fmaf(dv, p0.y, bb.y), 0.f));
            o[k * 4 + 2] = f2bf(fmaxf(fmaf(dv, p1.x, bb.z), 0.f));
            o[k * 4 + 3] = f2bf(fmaxf(fmaf(dv, p1.y, bb.w), 0.f));
        }
        *(ushort8_t*)(h2 + (size_t)v * 256 + sl * 16 + g * 8) = o;
    }
}

// ---------------- aggregation layer 2 (fp8 zp, 64B rows) + bias + log_softmax -------
__global__ __launch_bounds__(256) void k_agg2(const unsigned char* __restrict__ zp,
                                              const int* __restrict__ rowp,
                                              const int* __restrict__ col,
                                              const float* __restrict__ dinv,
                                              const float* __restrict__ b2,
                                              float* __restrict__ out, int n) {
    const unsigned int* __restrict__ zw = (const unsigned int*)zp;  // 16 uints/row
    const int w = threadIdx.x >> 6, lane = threadIdx.x & 63;
    const int g = lane >> 4, sl = lane & 15;
    const int v = blockIdx.x * 16 + w * 4 + g;
    if (v >= n) return;
    f32x2 a01, a23;
    {
        unsigned int u = zw[(size_t)v * 16 + sl];  // self-loop
        a01 = cvtpk0(u);
        a23 = cvtpk1(u);
    }
    const int e0 = rowp[v], e1 = rowp[v + 1];
    int e = e0;
    for (; e + 8 <= e1; e += 8) {
        int s0 = col[e], s1 = col[e + 1], s2 = col[e + 2], s3 = col[e + 3];
        int s4 = col[e + 4], s5 = col[e + 5], s6 = col[e + 6], s7 = col[e + 7];
        unsigned int u0 = zw[(size_t)s0 * 16 + sl];
        unsigned int u1 = zw[(size_t)s1 * 16 + sl];
        unsigned int u2 = zw[(size_t)s2 * 16 + sl];
        unsigned int u3 = zw[(size_t)s3 * 16 + sl];
        unsigned int u4 = zw[(size_t)s4 * 16 + sl];
        unsigned int u5 = zw[(size_t)s5 * 16 + sl];
        unsigned int u6 = zw[(size_t)s6 * 16 + sl];
        unsigned int u7 = zw[(size_t)s7 * 16 + sl];
        a01 += cvtpk0(u0) + cvtpk0(u1) + cvtpk0(u2) + cvtpk0(u3)
             + cvtpk0(u4) + cvtpk0(u5) + cvtpk0(u6) + cvtpk0(u7);
        a23 += cvtpk1(u0) + cvtpk1(u1) + cvtpk1(u2) + cvtpk1(u3)
             + cvtpk1(u4) + cvtpk1(u5) + cvtpk1(u6) + cvtpk1(u7);
    }
    for (; e + 2 <= e1; e += 2) {
        unsigned int u0 = zw[(size_t)col[e] * 16 + sl];
        unsigned int u1 = zw[(size_t)col[e + 1] * 16 + sl];
        a01 += cvtpk0(u0) + cvtpk0(u1);
        a23 += cvtpk1(u0) + cvtpk1(u1);
    }
    for (; e < e1; e++) {
        unsigned int u = zw[(size_t)col[e] * 16 + sl];
        a01 += cvtpk0(u);
        a23 += cvtpk1(u);
    }
    const int f = sl * 4;
    const float dv = dinv[v] * 0x1p-6f;  // undo fp8 range scale (64)
    float l0 = (f + 0 < 40) ? fmaf(dv, a01.x, b2[f + 0]) : -1e30f;
    float l1 = (f + 1 < 40) ? fmaf(dv, a01.y, b2[f + 1]) : -1e30f;
    float l2 = (f + 2 < 40) ? fmaf(dv, a23.x, b2[f + 2]) : -1e30f;
    float l3 = (f + 3 < 40) ? fmaf(dv, a23.y, b2[f + 3]) : -1e30f;
    float m = fmaxf(fmaxf(l0, l1), fmaxf(l2, l3));
    m = fmaxf(m, __shfl_xor(m, 1));
    m = fmaxf(m, __shfl_xor(m, 2));
    m = fmaxf(m, __shfl_xor(m, 4));
    m = fmaxf(m, __shfl_xor(m, 8));
    float es = expf(l0 - m) + expf(l1 - m) + expf(l2 - m) + expf(l3 - m);
    es += __shfl_xor(es, 1);
    es += __shfl_xor(es, 2);
    es += __shfl_xor(es, 4);
    es += __shfl_xor(es, 8);
    float ls = m + logf(es);
    if (sl < 10) {
        float4 o = {l0 - ls, l1 - ls, l2 - ls, l3 - ls};
        *(float4*)(out + (size_t)v * 40 + f) = o;
    }
}

extern "C" void kernel_launch(void* const* d_in, const int* in_sizes, int n_in,
                              void* d_out, int out_size, void* d_ws, size_t ws_size,
                              hipStream_t stream) {
    const float* x  = (const float*)d_in[0];
    const float* W1 = (const float*)d_in[1];
    const float* b1 = (const float*)d_in[2];
    const float* W2 = (const float*)d_in[3];
    const float* b2 = (const float*)d_in[4];
    const int*   ei = (const int*)d_in[5];
    float* out = (float*)d_out;

    const int FIN = 512, H = 256, C = 40;
    const int n = in_sizes[0] / FIN;   // 100000
    const int E = in_sizes[5] / 2;     // 3200000
    const int nbuck = (n + 127) >> 7;  // 782

    auto align_up = [](size_t v) { return (v + 255) & ~(size_t)255; };
    char* base = (char*)d_ws;
    size_t off = 0;
    unsigned char* h1p = (unsigned char*)(base + off); off += align_up((size_t)n * H);
    short* h2    = (short*)(base + off); off += align_up((size_t)n * H * 2);
    unsigned char* zp = (unsigned char*)(base + off); off += align_up((size_t)n * 64);
    float* dinv  = (float*)(base + off); off += align_up((size_t)n * 4);
    int* rowp    = (int*)(base + off);   off += align_up((size_t)(n + 1) * 4);
    int* colarr  = (int*)(base + off);   off += align_up((size_t)E * 4);
    int* slab    = (int*)(base + off);   off += align_up((size_t)nbuck * SLAB_CAP * 4);
    short* W1t   = (short*)(base + off); off += align_up((size_t)H * FIN * 2);
    short* W2t   = (short*)(base + off); off += align_up((size_t)64 * H * 2);
    int* bcnt    = (int*)(base + off);   off += align_up((size_t)(nbuck + 1) * 4);
    int* bbase   = (int*)(base + off);   off += align_up((size_t)(nbuck + 1) * 4);

    const int* srcp = ei;
    const int* dstp = ei + E;

    hipMemsetAsync(bcnt, 0, (size_t)(nbuck + 1) * 4, stream);
    hipMemsetAsync(W2t, 0, (size_t)64 * H * 2, stream);

    // CSR build (slab-bucketed), then wave-parallel per-dst rank sort
    k_bscatter<<<(E + 8191) / 8192, 256, 0, stream>>>(srcp, dstp, E, bcnt, slab, nbuck);
    k_bscan<<<1, 1024, 0, stream>>>(bcnt, bbase, nbuck);
    k_bcsr<<<nbuck, 256, 0, stream>>>(slab, bcnt, bbase, rowp, colarr, dinv, n, nbuck);
    k_sortcol<<<(n + 3) / 4, 256, 0, stream>>>(rowp, colarr, n);

    // weight prep
    int n1 = FIN * H, n2 = H * C;
    k_cvt_w<<<(n1 + n2 + 255) / 256, 256, 0, stream>>>(W1, W2, W1t, W2t, n1, n2);

    // layer 1: fused cast+GEMM -> fp8 h1p; row-gather aggregation -> h2
    k_gemm1<<<(n + 127) / 128, 512, 0, stream>>>(x, W1t, dinv, h1p, n);
    k_agg1<<<(n + 3) / 4, 256, 0, stream>>>(h1p, rowp, colarr, dinv, b1, h2, n);

    // layer 2: GEMM -> fp8 zp (64B rows); one-line-per-edge aggregation + log_softmax
    k_gemm2<<<(n + 127) / 128, 256, 0, stream>>>(h2, W2t, dinv, zp, n);
    k_agg2<<<(n + 15) / 16, 256, 0, stream>>>(zp, rowp, colarr, dinv, b2, out, n);
}

// Round 10
// 632.127 us; speedup vs baseline: 1.2879x; 1.0641x over previous
//
#include <hip/hip_runtime.h>
#include <stdint.h>

typedef __attribute__((ext_vector_type(8))) short bf16x8;
typedef __attribute__((ext_vector_type(4))) float f32x4;
typedef __attribute__((ext_vector_type(4))) int i32x4;
typedef __attribute__((ext_vector_type(2))) float f32x2;
typedef __attribute__((ext_vector_type(4))) unsigned int u32x4;
typedef __attribute__((ext_vector_type(8))) unsigned short ushort8_t;

__device__ __forceinline__ unsigned short f2bf(float f) {
    unsigned int u = __float_as_uint(f);
    u += 0x7FFFu + ((u >> 16) & 1u);
    return (unsigned short)(u >> 16);
}
__device__ __forceinline__ float bf2f(unsigned short s) {
    return __uint_as_float(((unsigned int)s) << 16);
}
// OCP e4m3fn encode (RNE) via exponent-shift trick; input pre-scaled into range.
__device__ __forceinline__ unsigned char fp8_enc(float f) {
    f = fminf(fmaxf(f, -448.f), 448.f);
    unsigned int u = __float_as_uint(f * 0x1p-120f);
    u += 0x7FFFFu + ((u >> 20) & 1u);
    return (unsigned char)(((u >> 20) & 0x7F) | ((u >> 24) & 0x80));
}

// packed fp8->f32 decode: word 0 = bytes 0,1 ; word 1 = bytes 2,3
__device__ __forceinline__ f32x2 cvtpk0(unsigned int u) {
#if __has_builtin(__builtin_amdgcn_cvt_pk_f32_fp8)
    auto r = __builtin_amdgcn_cvt_pk_f32_fp8((int)u, false);
    f32x2 o; o.x = r[0]; o.y = r[1]; return o;
#else
    f32x2 o;
    o.x = __builtin_amdgcn_cvt_f32_fp8(u, 0);
    o.y = __builtin_amdgcn_cvt_f32_fp8(u, 1);
    return o;
#endif
}
__device__ __forceinline__ f32x2 cvtpk1(unsigned int u) {
#if __has_builtin(__builtin_amdgcn_cvt_pk_f32_fp8)
    auto r = __builtin_amdgcn_cvt_pk_f32_fp8((int)u, true);
    f32x2 o; o.x = r[0]; o.y = r[1]; return o;
#else
    f32x2 o;
    o.x = __builtin_amdgcn_cvt_f32_fp8(u, 2);
    o.y = __builtin_amdgcn_cvt_f32_fp8(u, 3);
    return o;
#endif
}

#define SLAB_CAP 5120

// ---------------- bucketed CSR build (slab variant) ----------------
__global__ __launch_bounds__(256) void k_bscatter(const int* __restrict__ src,
                                                  const int* __restrict__ dst, int E,
                                                  int* __restrict__ bcnt,
                                                  int* __restrict__ slab, int nbuck) {
    __shared__ int lh[1024];
    __shared__ int lcur[1024];
    const int CH = 8192;
    int e0 = blockIdx.x * CH;
    int e1 = min(E, e0 + CH);
    for (int i = threadIdx.x; i < nbuck; i += 256) lh[i] = 0;
    __syncthreads();
    for (int i = e0 + threadIdx.x; i < e1; i += 256) atomicAdd(&lh[dst[i] >> 7], 1);
    __syncthreads();
    for (int i = threadIdx.x; i < nbuck; i += 256) {
        int c = lh[i];
        lh[i] = c ? atomicAdd(&bcnt[i], c) : 0;
        lcur[i] = 0;
    }
    __syncthreads();
    for (int i = e0 + threadIdx.x; i < e1; i += 256) {
        int d = dst[i], s = src[i];
        int b = d >> 7;
        int p = lh[b] + atomicAdd(&lcur[b], 1);
        if (p < SLAB_CAP) slab[(size_t)b * SLAB_CAP + p] = ((d & 127) << 20) | s;
    }
}

__global__ __launch_bounds__(1024) void k_bscan(const int* __restrict__ bcnt,
                                                int* __restrict__ bbase, int nbuck) {
    __shared__ int sh[1024];
    int t = threadIdx.x;
    int v = (t < nbuck) ? min(bcnt[t], SLAB_CAP) : 0;
    sh[t] = v;
    __syncthreads();
    for (int off = 1; off < 1024; off <<= 1) {
        int x = (t >= off) ? sh[t - off] : 0;
        __syncthreads();
        sh[t] += x;
        __syncthreads();
    }
    if (t < nbuck) bbase[t] = sh[t] - v;
    if (t == 1023) bbase[nbuck] = sh[1023];
}

__global__ __launch_bounds__(256) void k_bcsr(const int* __restrict__ slab,
                                              const int* __restrict__ bcnt,
                                              const int* __restrict__ bbase,
                                              int* __restrict__ rowp,
                                              int* __restrict__ col,
                                              float* __restrict__ dinv, int n, int nbuck) {
    __shared__ int lh[128], lsc[128], lcur[128];
    const int b = blockIdx.x;
    const int base = bbase[b];
    const int cnt = min(bcnt[b], SLAB_CAP);
    const int t = threadIdx.x;
    const int* sl = slab + (size_t)b * SLAB_CAP;
    if (t < 128) lh[t] = 0;
    __syncthreads();
    for (int i = t; i < cnt; i += 256) atomicAdd(&lh[sl[i] >> 20], 1);
    __syncthreads();
    if (t < 128) lsc[t] = lh[t];
    __syncthreads();
    for (int off = 1; off < 128; off <<= 1) {
        int x = (t < 128 && t >= off) ? lsc[t - off] : 0;
        __syncthreads();
        if (t < 128) lsc[t] += x;
        __syncthreads();
    }
    if (t < 128) {
        int excl = lsc[t] - lh[t];
        lcur[t] = excl;
        int v = (b << 7) + t;
        if (v < n) {
            rowp[v] = base + excl;
            dinv[v] = rsqrtf((float)lh[t] + 1.0f);  // +1 self-loop
        }
    }
    if (b == 0 && t == 0) rowp[n] = bbase[nbuck];
    __syncthreads();
    for (int i = t; i < cnt; i += 256) {
        int pk = sl[i];
        int d = pk >> 20;
        int p = base + atomicAdd(&lcur[d], 1);
        col[p] = pk & 0xFFFFF;
    }
}

// ---------------- weight prep ----------------
__global__ __launch_bounds__(256) void k_cvt_w(const float* __restrict__ W1,
                                               const float* __restrict__ W2,
                                               short* __restrict__ W1t,
                                               short* __restrict__ W2t,
                                               int n1, int n2) {
    int i = blockIdx.x * blockDim.x + threadIdx.x;
    if (i < n1) {
        int k = i >> 8, c = i & 255;
        W1t[(size_t)c * 512 + k] = (short)f2bf(W1[i]);
    } else if (i < n1 + n2) {
        int i2 = i - n1;
        int k = i2 / 40, c = i2 - k * 40;
        W2t[(size_t)c * 256 + k] = (short)f2bf(W2[i2]);
    }
}

// ---------------- GEMM1: A f32 [M][512] x W1t bf16 [256][512] -> h1p fp8 [M][256] ---
__global__ __launch_bounds__(512) void k_gemm1(const float* __restrict__ A,
                                               const short* __restrict__ Bt,
                                               const float* __restrict__ dinv,
                                               unsigned char* __restrict__ outp, int M) {
    const int K = 512;
    __shared__ __align__(16) short As[128 * 32];
    __shared__ __align__(16) short Bs[256 * 32];
    const int tid = threadIdx.x;
    const int m0 = blockIdx.x * 128;
    const int w = tid >> 6, lane = tid & 63;
    const int quad = lane >> 4, l16 = lane & 15;
    const int mbase = (w >> 2) * 64, nbase = (w & 3) * 64;

    f32x4 acc[4][4];
#pragma unroll
    for (int i = 0; i < 4; i++)
#pragma unroll
        for (int j = 0; j < 4; j++) acc[i][j] = (f32x4){0.f, 0.f, 0.f, 0.f};

    for (int k0 = 0; k0 < K; k0 += 32) {
#pragma unroll
        for (int s = tid; s < 1024; s += 512) {
            int r = s >> 3, seg = s & 7;
            int gr = m0 + r;
            if (gr >= M) gr = M - 1;
            float4 v = *(const float4*)(A + (size_t)gr * K + k0 + seg * 4);
            ushort4 o;
            o.x = f2bf(v.x); o.y = f2bf(v.y); o.z = f2bf(v.z); o.w = f2bf(v.w);
            *(ushort4*)(As + r * 32 + seg * 4) = o;
        }
#pragma unroll
        for (int s = tid; s < 1024; s += 512) {
            int r = s >> 2, seg = s & 3;
            i32x4 v = *(const i32x4*)(Bt + (size_t)r * K + k0 + seg * 8);
            *(i32x4*)(Bs + r * 32 + seg * 8) = v;
        }
        __syncthreads();
        bf16x8 af[4], bfr[4];
#pragma unroll
        for (int i = 0; i < 4; i++)
            af[i] = *(const bf16x8*)(As + (mbase + i * 16 + l16) * 32 + quad * 8);
#pragma unroll
        for (int j = 0; j < 4; j++)
            bfr[j] = *(const bf16x8*)(Bs + (nbase + j * 16 + l16) * 32 + quad * 8);
#pragma unroll
        for (int i = 0; i < 4; i++)
#pragma unroll
            for (int j = 0; j < 4; j++)
                acc[i][j] = __builtin_amdgcn_mfma_f32_16x16x32_bf16(af[i], bfr[j], acc[i][j], 0, 0, 0);
        __syncthreads();
    }

#pragma unroll
    for (int i = 0; i < 4; i++) {
#pragma unroll
        for (int r = 0; r < 4; r++) {
            int row = m0 + mbase + i * 16 + quad * 4 + r;
            if (row < M) {
                float dv = dinv[row] * 64.f;  // fp8 range scale; undone in agg1
#pragma unroll
                for (int j = 0; j < 4; j++)
                    outp[(size_t)row * 256 + nbase + j * 16 + l16] =
                        fp8_enc(acc[i][j][r] * dv);
            }
        }
    }
}

// ---------------- GEMM2: h2 bf16 [M][256] x W2t bf16 [64][256] -> zp fp8 [M][64] ----
__global__ __launch_bounds__(256) void k_gemm2(const short* __restrict__ A,
                                               const short* __restrict__ Bt,
                                               const float* __restrict__ dinv,
                                               unsigned char* __restrict__ outp, int M) {
    const int K = 256;
    __shared__ __align__(16) short As[128 * 32];
    __shared__ __align__(16) short Bs[64 * 32];
    const int tid = threadIdx.x;
    const int m0 = blockIdx.x * 128;
    const int w = tid >> 6, lane = tid & 63;
    const int quad = lane >> 4, l16 = lane & 15;
    const int mbase = (w >> 1) * 64, nbase = (w & 1) * 32;

    f32x4 acc[4][2];
#pragma unroll
    for (int i = 0; i < 4; i++)
#pragma unroll
        for (int j = 0; j < 2; j++) acc[i][j] = (f32x4){0.f, 0.f, 0.f, 0.f};

    for (int k0 = 0; k0 < K; k0 += 32) {
#pragma unroll
        for (int s = tid; s < 512; s += 256) {
            int r = s >> 2, seg = s & 3;
            int gr = m0 + r;
            if (gr >= M) gr = M - 1;
            i32x4 v = *(const i32x4*)(A + (size_t)gr * K + k0 + seg * 8);
            *(i32x4*)(As + r * 32 + seg * 8) = v;
        }
        if (tid < 256) {
            int r = tid >> 2, seg = tid & 3;
            i32x4 v = *(const i32x4*)(Bt + (size_t)r * K + k0 + seg * 8);
            *(i32x4*)(Bs + r * 32 + seg * 8) = v;
        }
        __syncthreads();
        bf16x8 af[4], bfr[2];
#pragma unroll
        for (int i = 0; i < 4; i++)
            af[i] = *(const bf16x8*)(As + (mbase + i * 16 + l16) * 32 + quad * 8);
#pragma unroll
        for (int j = 0; j < 2; j++)
            bfr[j] = *(const bf16x8*)(Bs + (nbase + j * 16 + l16) * 32 + quad * 8);
#pragma unroll
        for (int i = 0; i < 4; i++)
#pragma unroll
            for (int j = 0; j < 2; j++)
                acc[i][j] = __builtin_amdgcn_mfma_f32_16x16x32_bf16(af[i], bfr[j], acc[i][j], 0, 0, 0);
        __syncthreads();
    }

#pragma unroll
    for (int i = 0; i < 4; i++) {
#pragma unroll
        for (int r = 0; r < 4; r++) {
            int row = m0 + mbase + i * 16 + quad * 4 + r;
            if (row < M) {
                float dv = dinv[row] * 64.f;  // fp8 range scale; undone in agg2
#pragma unroll
                for (int j = 0; j < 2; j++)
                    outp[(size_t)row * 64 + nbase + j * 16 + l16] =
                        fp8_enc(acc[i][j][r] * dv);
            }
        }
    }
}

// ---------------- aggregation layer 1 (256 feats, fp8 payload), bias+relu ----------
// 16 lanes per edge, dwordx4 gathers (one load instr = 4 edges' 256B rows),
// 2-deep unroll (2 KB in flight/wave), packed fp8 decode + f32x2 accumulation.
// Measured-best structure (633.4 us total, R1). Pattern-ceiling-bound at
// ~3.3 TB/s on the random-gather miss path (5 structural variants tried).
__global__ __launch_bounds__(256) void k_agg1(const unsigned char* __restrict__ h1p,
                                              const int* __restrict__ rowp,
                                              const int* __restrict__ col,
                                              const float* __restrict__ dinv,
                                              const float* __restrict__ b1,
                                              short* __restrict__ h2, int n) {
    const u32x4* __restrict__ hq = (const u32x4*)h1p;  // 16 x 16B per row
    const int w = threadIdx.x >> 6, lane = threadIdx.x & 63;
    const int g = lane >> 4, sl = lane & 15;  // 4 edge-groups x 16 lanes
    const int v = blockIdx.x * 4 + w;         // one dst per wave
    if (v >= n) return;

    f32x2 acc[8];  // 16 feats per lane: feats sl*16 .. sl*16+15
    {
        u32x4 q = (u32x4){0u, 0u, 0u, 0u};
        if (g == 0) q = hq[(size_t)v * 16 + sl];  // self-loop once (group 0)
#pragma unroll
        for (int i = 0; i < 4; i++) {
            acc[2 * i] = cvtpk0(q[i]);
            acc[2 * i + 1] = cvtpk1(q[i]);
        }
    }

    const int e0 = rowp[v], e1 = rowp[v + 1];
    const int nedge = e1 - e0;
    const int full = nedge & ~7;  // wave-uniform
    for (int t = 0; t < full; t += 8) {
        int ea = e0 + t + g;
        int sa = col[ea], sb = col[ea + 4];
        u32x4 qa = hq[(size_t)sa * 16 + sl];
        u32x4 qb = hq[(size_t)sb * 16 + sl];
#pragma unroll
        for (int i = 0; i < 4; i++) {
            acc[2 * i] += cvtpk0(qa[i]);
            acc[2 * i + 1] += cvtpk1(qa[i]);
        }
#pragma unroll
        for (int i = 0; i < 4; i++) {
            acc[2 * i] += cvtpk0(qb[i]);
            acc[2 * i + 1] += cvtpk1(qb[i]);
        }
    }
    for (int t = full + g; t < nedge; t += 4) {  // tail: <=2 predicated rounds
        u32x4 q = hq[(size_t)col[e0 + t] * 16 + sl];
#pragma unroll
        for (int i = 0; i < 4; i++) {
            acc[2 * i] += cvtpk0(q[i]);
            acc[2 * i + 1] += cvtpk1(q[i]);
        }
    }

    // reduce across the 4 edge-groups (once per dst)
#pragma unroll
    for (int i = 0; i < 8; i++) {
        acc[i].x += __shfl_xor(acc[i].x, 16);
        acc[i].y += __shfl_xor(acc[i].y, 16);
        acc[i].x += __shfl_xor(acc[i].x, 32);
        acc[i].y += __shfl_xor(acc[i].y, 32);
    }

    if (g < 2) {  // groups 0,1 each store 16B -> one 512B coalesced row store
        const float dv = dinv[v] * 0x1p-6f;  // undo fp8 range scale (64)
        const float4* bq = (const float4*)(b1 + sl * 16 + g * 8);
        ushort8_t o;
#pragma unroll
        for (int k = 0; k < 2; k++) {
            float4 bb = bq[k];
            f32x2 p0 = acc[g * 4 + k * 2];
            f32x2 p1 = acc[g * 4 + k * 2 + 1];
            o[k * 4 + 0] = f2bf(fmaxf(fmaf(dv, p0.x, bb.x), 0.f));
            o[k * 4 + 1] = f2bf(fmaxf(fmaf(dv, p0.y, bb.y), 0.f));
            o[k * 4 + 2] = f2bf(fmaxf(fmaf(dv, p1.x, bb.z), 0.f));
            o[k * 4 + 3] = f2bf(fmaxf(fmaf(dv, p1.y, bb.w), 0.f));
        }
        *(ushort8_t*)(h2 + (size_t)v * 256 + sl * 16 + g * 8) = o;
    }
}

// ---------------- aggregation layer 2 (fp8 zp, 64B rows) + bias + log_softmax -------
// 16 lanes per dst, packed fp8 decode, 8-deep unroll (2KB in flight/wave).
__global__ __launch_bounds__(256) void k_agg2(const unsigned char* __restrict__ zp,
                                              const int* __restrict__ rowp,
                                              const int* __restrict__ col,
                                              const float* __restrict__ dinv,
                                              const float* __restrict__ b2,
                                              float* __restrict__ out, int n) {
    const unsigned int* __restrict__ zw = (const unsigned int*)zp;  // 16 uints/row
    const int w = threadIdx.x >> 6, lane = threadIdx.x & 63;
    const int g = lane >> 4, sl = lane & 15;
    const int v = blockIdx.x * 16 + w * 4 + g;
    if (v >= n) return;
    f32x2 a01, a23;
    {
        unsigned int u = zw[(size_t)v * 16 + sl];  // self-loop
        a01 = cvtpk0(u);
        a23 = cvtpk1(u);
    }
    const int e0 = rowp[v], e1 = rowp[v + 1];
    int e = e0;
    for (; e + 8 <= e1; e += 8) {
        int s0 = col[e], s1 = col[e + 1], s2 = col[e + 2], s3 = col[e + 3];
        int s4 = col[e + 4], s5 = col[e + 5], s6 = col[e + 6], s7 = col[e + 7];
        unsigned int u0 = zw[(size_t)s0 * 16 + sl];
        unsigned int u1 = zw[(size_t)s1 * 16 + sl];
        unsigned int u2 = zw[(size_t)s2 * 16 + sl];
        unsigned int u3 = zw[(size_t)s3 * 16 + sl];
        unsigned int u4 = zw[(size_t)s4 * 16 + sl];
        unsigned int u5 = zw[(size_t)s5 * 16 + sl];
        unsigned int u6 = zw[(size_t)s6 * 16 + sl];
        unsigned int u7 = zw[(size_t)s7 * 16 + sl];
        a01 += cvtpk0(u0) + cvtpk0(u1) + cvtpk0(u2) + cvtpk0(u3)
             + cvtpk0(u4) + cvtpk0(u5) + cvtpk0(u6) + cvtpk0(u7);
        a23 += cvtpk1(u0) + cvtpk1(u1) + cvtpk1(u2) + cvtpk1(u3)
             + cvtpk1(u4) + cvtpk1(u5) + cvtpk1(u6) + cvtpk1(u7);
    }
    for (; e + 2 <= e1; e += 2) {
        unsigned int u0 = zw[(size_t)col[e] * 16 + sl];
        unsigned int u1 = zw[(size_t)col[e + 1] * 16 + sl];
        a01 += cvtpk0(u0) + cvtpk0(u1);
        a23 += cvtpk1(u0) + cvtpk1(u1);
    }
    for (; e < e1; e++) {
        unsigned int u = zw[(size_t)col[e] * 16 + sl];
        a01 += cvtpk0(u);
        a23 += cvtpk1(u);
    }
    const int f = sl * 4;
    const float dv = dinv[v] * 0x1p-6f;  // undo fp8 range scale (64)
    float l0 = (f + 0 < 40) ? fmaf(dv, a01.x, b2[f + 0]) : -1e30f;
    float l1 = (f + 1 < 40) ? fmaf(dv, a01.y, b2[f + 1]) : -1e30f;
    float l2 = (f + 2 < 40) ? fmaf(dv, a23.x, b2[f + 2]) : -1e30f;
    float l3 = (f + 3 < 40) ? fmaf(dv, a23.y, b2[f + 3]) : -1e30f;
    float m = fmaxf(fmaxf(l0, l1), fmaxf(l2, l3));
    m = fmaxf(m, __shfl_xor(m, 1));
    m = fmaxf(m, __shfl_xor(m, 2));
    m = fmaxf(m, __shfl_xor(m, 4));
    m = fmaxf(m, __shfl_xor(m, 8));
    float es = expf(l0 - m) + expf(l1 - m) + expf(l2 - m) + expf(l3 - m);
    es += __shfl_xor(es, 1);
    es += __shfl_xor(es, 2);
    es += __shfl_xor(es, 4);
    es += __shfl_xor(es, 8);
    float ls = m + logf(es);
    if (sl < 10) {
        float4 o = {l0 - ls, l1 - ls, l2 - ls, l3 - ls};
        *(float4*)(out + (size_t)v * 40 + f) = o;
    }
}

extern "C" void kernel_launch(void* const* d_in, const int* in_sizes, int n_in,
                              void* d_out, int out_size, void* d_ws, size_t ws_size,
                              hipStream_t stream) {
    const float* x  = (const float*)d_in[0];
    const float* W1 = (const float*)d_in[1];
    const float* b1 = (const float*)d_in[2];
    const float* W2 = (const float*)d_in[3];
    const float* b2 = (const float*)d_in[4];
    const int*   ei = (const int*)d_in[5];
    float* out = (float*)d_out;

    const int FIN = 512, H = 256, C = 40;
    const int n = in_sizes[0] / FIN;   // 100000
    const int E = in_sizes[5] / 2;     // 3200000
    const int nbuck = (n + 127) >> 7;  // 782

    auto align_up = [](size_t v) { return (v + 255) & ~(size_t)255; };
    char* base = (char*)d_ws;
    size_t off = 0;
    unsigned char* h1p = (unsigned char*)(base + off); off += align_up((size_t)n * H);
    short* h2    = (short*)(base + off); off += align_up((size_t)n * H * 2);
    unsigned char* zp = (unsigned char*)(base + off); off += align_up((size_t)n * 64);
    float* dinv  = (float*)(base + off); off += align_up((size_t)n * 4);
    int* rowp    = (int*)(base + off);   off += align_up((size_t)(n + 1) * 4);
    int* colarr  = (int*)(base + off);   off += align_up((size_t)E * 4);
    int* slab    = (int*)(base + off);   off += align_up((size_t)nbuck * SLAB_CAP * 4);
    short* W1t   = (short*)(base + off); off += align_up((size_t)H * FIN * 2);
    short* W2t   = (short*)(base + off); off += align_up((size_t)64 * H * 2);
    int* bcnt    = (int*)(base + off);   off += align_up((size_t)(nbuck + 1) * 4);
    int* bbase   = (int*)(base + off);   off += align_up((size_t)(nbuck + 1) * 4);

    const int* srcp = ei;
    const int* dstp = ei + E;

    hipMemsetAsync(bcnt, 0, (size_t)(nbuck + 1) * 4, stream);
    hipMemsetAsync(W2t, 0, (size_t)64 * H * 2, stream);

    // CSR build (slab-bucketed)
    k_bscatter<<<(E + 8191) / 8192, 256, 0, stream>>>(srcp, dstp, E, bcnt, slab, nbuck);
    k_bscan<<<1, 1024, 0, stream>>>(bcnt, bbase, nbuck);
    k_bcsr<<<nbuck, 256, 0, stream>>>(slab, bcnt, bbase, rowp, colarr, dinv, n, nbuck);

    // weight prep
    int n1 = FIN * H, n2 = H * C;
    k_cvt_w<<<(n1 + n2 + 255) / 256, 256, 0, stream>>>(W1, W2, W1t, W2t, n1, n2);

    // layer 1: fused cast+GEMM -> fp8 h1p; row-gather aggregation -> h2
    k_gemm1<<<(n + 127) / 128, 512, 0, stream>>>(x, W1t, dinv, h1p, n);
    k_agg1<<<(n + 3) / 4, 256, 0, stream>>>(h1p, rowp, colarr, dinv, b1, h2, n);

    // layer 2: GEMM -> fp8 zp (64B rows); one-line-per-edge aggregation + log_softmax
    k_gemm2<<<(n + 127) / 128, 256, 0, stream>>>(h2, W2t, dinv, zp, n);
    k_agg2<<<(n + 15) / 16, 256, 0, stream>>>(zp, rowp, colarr, dinv, b2, out, n);
}